// Round 6
// baseline (227.913 us; speedup 1.0000x reference)
//
#include <hip/hip_runtime.h>
#include <stdint.h>

#define NB 16
#define LQ 2048
#define LK 2048
#define DH 64
#define QT 16
#define NW 16                 // waves per block
#define STRIP (NW * 16)       // 256 keys per phase-1 iteration
#define NIT (LK / STRIP)      // 8

typedef short bf16x8 __attribute__((ext_vector_type(8)));
typedef float f32x4 __attribute__((ext_vector_type(4)));

__device__ __forceinline__ unsigned short f2bf(float f) {
    union { float f; uint32_t u; } v; v.f = f;
    uint32_t u = v.u;
    u += 0x7FFFu + ((u >> 16) & 1u);   // RNE; inputs finite/bounded
    return (unsigned short)(u >> 16);
}
__device__ __forceinline__ float bf2f(unsigned short h) {
    union { uint32_t u; float f; } v; v.u = ((uint32_t)h) << 16;
    return v.f;
}
__device__ __forceinline__ uint32_t pack2(float lo, float hi) {
    return (uint32_t)f2bf(lo) | ((uint32_t)f2bf(hi) << 16);
}

// ---------------- pre-pass: f32 -> bf16 (Q, K) and f32 -> bf16 transposed (V) ----
__global__ void convert_kernel(const float* __restrict__ q, const float* __restrict__ k,
                               const float* __restrict__ v,
                               unsigned short* __restrict__ qb,
                               unsigned short* __restrict__ kb,
                               unsigned short* __restrict__ vtb) {
    int bid = blockIdx.x;
    int tid = threadIdx.x;
    if (bid < 2048) {
        const float* src = (bid < 1024) ? q : k;
        unsigned short* dst = (bid < 1024) ? qb : kb;
        int64_t off = (int64_t)(bid & 1023) * 2048 + (int64_t)tid * 8;
        float4 a = *(const float4*)(src + off);
        float4 b4 = *(const float4*)(src + off + 4);
        uint4 o;
        o.x = pack2(a.x, a.y);
        o.y = pack2(a.z, a.w);
        o.z = pack2(b4.x, b4.y);
        o.w = pack2(b4.z, b4.w);
        *(uint4*)(dst + off) = o;
    } else {
        __shared__ unsigned short tile[64][72];
        int bid2 = bid - 2048;
        int bb = bid2 >> 5, kt = bid2 & 31;
        int k0 = kt * 64;
        int krow = tid >> 2, dc = (tid & 3) * 16;
        const float* vp = v + ((int64_t)(bb * LK) + k0 + krow) * DH + dc;
        float4 x0 = *(const float4*)(vp);
        float4 x1 = *(const float4*)(vp + 4);
        float4 x2 = *(const float4*)(vp + 8);
        float4 x3 = *(const float4*)(vp + 12);
        float vals[16] = {x0.x, x0.y, x0.z, x0.w, x1.x, x1.y, x1.z, x1.w,
                          x2.x, x2.y, x2.z, x2.w, x3.x, x3.y, x3.z, x3.w};
        #pragma unroll
        for (int i = 0; i < 16; ++i) tile[dc + i][krow] = f2bf(vals[i]);
        __syncthreads();
        int d = tid >> 2, kc = (tid & 3) * 16;
        uint4 r0 = *(const uint4*)&tile[d][kc];
        uint4 r1 = *(const uint4*)&tile[d][kc + 8];
        unsigned short* op = vtb + ((int64_t)(bb * DH) + d) * LK + k0 + kc;
        *(uint4*)op = r0;
        *(uint4*)(op + 8) = r1;
    }
}

// ---------------- fused attention ------------------------------------------------
// grid 2048 (16 b x 128 q-tiles), 1024 threads (16 waves), QT=16 rows/block.
// LDS: e[16][2048] bf16 (XOR-swizzled) 65536 + denom_part[16][16] 1024 + denF[16]
// 64 + pp[12][16][16] 12288 = 78912 B -> 2 blocks/CU, 32 waves/CU.
__launch_bounds__(1024, 8)
__global__ void attn_kernel(const unsigned short* __restrict__ qb,
                            const unsigned short* __restrict__ kb,
                            const unsigned short* __restrict__ vtb,
                            const float* __restrict__ mask,
                            float* __restrict__ out, float* __restrict__ attn) {
    extern __shared__ char smem[];
    float* denom_part = (float*)(smem + QT * LK * 2);              // [16][16]
    float* denF       = (float*)(smem + QT * LK * 2 + 1024);       // [16]
    float* pp         = (float*)(smem + QT * LK * 2 + 1088);       // [12][16][16]

    int bid = blockIdx.x;
    int swz = (bid & 7) * 256 + (bid >> 3);   // bijective XCD swizzle (2048 % 8 == 0)
    int b = swz >> 7;
    int q0 = (swz & 127) * QT;

    int tid = threadIdx.x;
    int lane = tid & 63;
    int wave = tid >> 6;
    int lr = lane & 15, lg = lane >> 4;

    // Q fragments (B-operand of S^T = K·Q^T): lane holds Q[q0+lr][8*lg+i]
    bf16x8 qf0, qf1;
    {
        const unsigned short* qp = qb + ((int64_t)(b * LQ + q0 + lr)) * DH + 8 * lg;
        qf0 = *(const bf16x8*)qp;
        qf1 = *(const bf16x8*)(qp + 32);
    }

    float dsum = 0.f;

    // ---- phase 1: S^T MFMA + inline mask-select + exp -> LDS; mask streams
    //      from HBM underneath the MFMA/exp compute (2-deep prefetch). ----
    {
        const unsigned short* kpw =
            kb + (int64_t)b * LK * DH + (wave * 16 + lr) * DH + 8 * lg;
        const float* mrow =
            mask + ((int64_t)(b * LQ + q0 + lr)) * LK + wave * 16 + lg * 4;
        bf16x8 kf0 = *(const bf16x8*)kpw;
        bf16x8 kf1 = *(const bf16x8*)(kpw + 32);
        float4 mcur = *(const float4*)mrow;
        float4 mn1  = *(const float4*)(mrow + STRIP);
        #pragma unroll
        for (int kt = 0; kt < NIT; ++kt) {
            float4 mn2;
            if (kt + 2 < NIT) mn2 = *(const float4*)(mrow + (kt + 2) * STRIP);
            bf16x8 nk0, nk1;
            if (kt + 1 < NIT) {
                const unsigned short* np = kpw + (int64_t)(kt + 1) * STRIP * DH;
                nk0 = *(const bf16x8*)np;
                nk1 = *(const bf16x8*)(np + 32);
            }
            f32x4 acc = {0.f, 0.f, 0.f, 0.f};
            acc = __builtin_amdgcn_mfma_f32_16x16x32_bf16(kf0, qf0, acc, 0, 0, 0);
            acc = __builtin_amdgcn_mfma_f32_16x16x32_bf16(kf1, qf1, acc, 0, 0, 0);
            // C[row=lg*4+j][col=lr] = S[q=lr][key = kt*STRIP + wave*16 + lg*4 + j]
            float mv[4] = {mcur.x, mcur.y, mcur.z, mcur.w};
            unsigned short eb[4];
            #pragma unroll
            for (int j = 0; j < 4; ++j) {
                float s = acc[j] * 0.125f;
                s = fminf(fmaxf(s, -15.0f), 15.0f);
                unsigned short p = f2bf(__expf(s));
                eb[j] = (mv[j] != 0.f) ? p : (unsigned short)0;
                dsum += bf2f(eb[j]);
            }
            uint2 u;
            u.x = (uint32_t)eb[0] | ((uint32_t)eb[1] << 16);
            u.y = (uint32_t)eb[2] | ((uint32_t)eb[3] << 16);
            int c = kt * STRIP + wave * 16 + lg * 4;
            int byteoff = (lr * 4096 + c * 2) ^ ((lr & 7) << 4);
            *(uint2*)(smem + byteoff) = u;
            kf0 = nk0; kf1 = nk1;
            mcur = mn1; mn1 = mn2;
        }
    }

    // per-row partial denominators: sum over lg (4 lanes per row)
    dsum += __shfl_xor(dsum, 16);
    dsum += __shfl_xor(dsum, 32);
    if (lane < 16) denom_part[wave * 16 + lane] = dsum;
    __syncthreads();

    // ---- phase 2: attn row write-out (nt stores, fire-and-forget) ----
    {
        int r = wave;
        float den = 1e-6f;
        #pragma unroll
        for (int w = 0; w < NW; ++w) den += denom_part[w * 16 + r];
        if (lane == 0) denF[r] = den;
        float inv = 1.0f / den;
        float* ap = attn + ((int64_t)(b * LQ + q0 + r)) * LK;
        int rowbase = r * 4096;
        int sw = (r & 7) << 4;
        int c0l = lane * 8;
        #pragma unroll
        for (int i = 0; i < 4; ++i) {
            int byteoff = (rowbase + (i * 512 + c0l) * 2) ^ sw;
            bf16x8 ev = *(const bf16x8*)(smem + byteoff);
            f32x4 o0, o1;
            o0[0] = bf2f((unsigned short)ev[0]) * inv;
            o0[1] = bf2f((unsigned short)ev[1]) * inv;
            o0[2] = bf2f((unsigned short)ev[2]) * inv;
            o0[3] = bf2f((unsigned short)ev[3]) * inv;
            o1[0] = bf2f((unsigned short)ev[4]) * inv;
            o1[1] = bf2f((unsigned short)ev[5]) * inv;
            o1[2] = bf2f((unsigned short)ev[6]) * inv;
            o1[3] = bf2f((unsigned short)ev[7]) * inv;
            __builtin_nontemporal_store(o0, (f32x4*)(ap + i * 512 + c0l));
            __builtin_nontemporal_store(o1, (f32x4*)(ap + i * 512 + c0l + 4));
        }
    }

    // ---- phase 3: PV; wave w -> col-tile (w&3)*16, K-quarter w>>2 ----
    f32x4 pacc = {0.f, 0.f, 0.f, 0.f};
    int cw = (wave & 3) * 16, kq = wave >> 2;
    {
        const unsigned short* vp =
            vtb + ((int64_t)(b * DH + cw + lr)) * LK + kq * 512 + 8 * lg;
        int rowbase = lr * 4096;
        int sw = (lr & 7) << 4;
        int kk0 = kq * 512;
        #pragma unroll 4
        for (int kk = 0; kk < 512; kk += 32) {
            int byteoff = (rowbase + (kk0 + kk + 8 * lg) * 2) ^ sw;
            bf16x8 ef = *(const bf16x8*)(smem + byteoff);
            bf16x8 vf = *(const bf16x8*)(vp + kk);
            pacc = __builtin_amdgcn_mfma_f32_16x16x32_bf16(ef, vf, pacc, 0, 0, 0);
        }
    }
    if (kq != 0) {
        #pragma unroll
        for (int j = 0; j < 4; ++j)
            pp[((kq - 1) * 4 + (wave & 3)) * 256 + (lg * 4 + j) * 16 + lr] = pacc[j];
    }
    __syncthreads();
    if (kq == 0) {
        int c4 = wave & 3;
        #pragma unroll
        for (int j = 0; j < 4; ++j) {
            int r = lg * 4 + j;
            float den = denF[r];
            float val = pacc[j] + pp[(c4) * 256 + r * 16 + lr] +
                        pp[(4 + c4) * 256 + r * 16 + lr] +
                        pp[(8 + c4) * 256 + r * 16 + lr];
            out[((int64_t)(b * LQ + q0 + r)) * DH + cw + lr] = val / den;
        }
    }
}

extern "C" void kernel_launch(void* const* d_in, const int* in_sizes, int n_in,
                              void* d_out, int out_size, void* d_ws, size_t ws_size,
                              hipStream_t stream) {
    const float* q    = (const float*)d_in[0];
    const float* k    = (const float*)d_in[1];
    const float* v    = (const float*)d_in[2];
    const float* mask = (const float*)d_in[3];
    float* out  = (float*)d_out;
    float* attn = out + (int64_t)NB * LQ * DH;

    unsigned short* qb  = (unsigned short*)d_ws;
    unsigned short* kb  = qb + (int64_t)NB * LQ * DH;
    unsigned short* vtb = kb + (int64_t)NB * LK * DH;

    (void)hipFuncSetAttribute((const void*)attn_kernel,
                              hipFuncAttributeMaxDynamicSharedMemorySize, 78912);

    convert_kernel<<<2560, 256, 0, stream>>>(q, k, v, qb, kb, vtb);
    attn_kernel<<<2048, 1024, 78912, stream>>>(qb, kb, vtb, mask, out, attn);
}

// Round 7
// 215.635 us; speedup vs baseline: 1.0569x; 1.0569x over previous
//
#include <hip/hip_runtime.h>
#include <stdint.h>

#define NB 16
#define LQ 2048
#define LK 2048
#define DH 64
#define QT 16
#define NW 16                 // waves per block
#define STRIP (NW * 16)       // 256 keys per phase-1 iteration
#define NIT (LK / STRIP)      // 8

typedef short bf16x8 __attribute__((ext_vector_type(8)));
typedef float f32x4 __attribute__((ext_vector_type(4)));

__device__ __forceinline__ unsigned short f2bf(float f) {
    union { float f; uint32_t u; } v; v.f = f;
    uint32_t u = v.u;
    u += 0x7FFFu + ((u >> 16) & 1u);   // RNE; inputs finite/bounded
    return (unsigned short)(u >> 16);
}
__device__ __forceinline__ float bf2f(unsigned short h) {
    union { uint32_t u; float f; } v; v.u = ((uint32_t)h) << 16;
    return v.f;
}
__device__ __forceinline__ uint32_t pack2(float lo, float hi) {
    return (uint32_t)f2bf(lo) | ((uint32_t)f2bf(hi) << 16);
}

// ---------------- pre-pass: f32 -> bf16 (Q, K) and f32 -> bf16 transposed (V) ----
__global__ void convert_kernel(const float* __restrict__ q, const float* __restrict__ k,
                               const float* __restrict__ v,
                               unsigned short* __restrict__ qb,
                               unsigned short* __restrict__ kb,
                               unsigned short* __restrict__ vtb) {
    int bid = blockIdx.x;
    int tid = threadIdx.x;
    if (bid < 2048) {
        const float* src = (bid < 1024) ? q : k;
        unsigned short* dst = (bid < 1024) ? qb : kb;
        int64_t off = (int64_t)(bid & 1023) * 2048 + (int64_t)tid * 8;
        float4 a = *(const float4*)(src + off);
        float4 b4 = *(const float4*)(src + off + 4);
        uint4 o;
        o.x = pack2(a.x, a.y);
        o.y = pack2(a.z, a.w);
        o.z = pack2(b4.x, b4.y);
        o.w = pack2(b4.z, b4.w);
        *(uint4*)(dst + off) = o;
    } else {
        __shared__ unsigned short tile[64][72];
        int bid2 = bid - 2048;
        int bb = bid2 >> 5, kt = bid2 & 31;
        int k0 = kt * 64;
        int krow = tid >> 2, dc = (tid & 3) * 16;
        const float* vp = v + ((int64_t)(bb * LK) + k0 + krow) * DH + dc;
        float4 x0 = *(const float4*)(vp);
        float4 x1 = *(const float4*)(vp + 4);
        float4 x2 = *(const float4*)(vp + 8);
        float4 x3 = *(const float4*)(vp + 12);
        float vals[16] = {x0.x, x0.y, x0.z, x0.w, x1.x, x1.y, x1.z, x1.w,
                          x2.x, x2.y, x2.z, x2.w, x3.x, x3.y, x3.z, x3.w};
        #pragma unroll
        for (int i = 0; i < 16; ++i) tile[dc + i][krow] = f2bf(vals[i]);
        __syncthreads();
        int d = tid >> 2, kc = (tid & 3) * 16;
        uint4 r0 = *(const uint4*)&tile[d][kc];
        uint4 r1 = *(const uint4*)&tile[d][kc + 8];
        unsigned short* op = vtb + ((int64_t)(bb * DH) + d) * LK + k0 + kc;
        *(uint4*)op = r0;
        *(uint4*)(op + 8) = r1;
    }
}

// asm load helpers: opaque to the compiler's scheduler; issue order preserved
// (volatile asm are not reordered against each other).
__device__ __forceinline__ void ld_f32x4(f32x4& d, const float* p) {
    asm volatile("global_load_dwordx4 %0, %1, off" : "=v"(d) : "v"((uint64_t)p));
}
__device__ __forceinline__ void ld_bf16x8(bf16x8& d, const unsigned short* p) {
    asm volatile("global_load_dwordx4 %0, %1, off" : "=v"(d) : "v"((uint64_t)p));
}

// ---------------- fused attention ------------------------------------------------
// grid 2048 (16 b x 128 q-tiles), 1024 threads (16 waves), QT=16 rows/block.
// LDS: e[16][2048] bf16 (XOR-swizzled) 65536 + denom_part[16][16] 1024 + denF[16]
// 64 + pp[12][16][16] 12288 = 78912 B -> 2 blocks/CU, 32 waves/CU.
__launch_bounds__(1024, 8)
__global__ void attn_kernel(const unsigned short* __restrict__ qb,
                            const unsigned short* __restrict__ kb,
                            const unsigned short* __restrict__ vtb,
                            const float* __restrict__ mask,
                            float* __restrict__ out, float* __restrict__ attn) {
    extern __shared__ char smem[];
    float* denom_part = (float*)(smem + QT * LK * 2);              // [16][16]
    float* denF       = (float*)(smem + QT * LK * 2 + 1024);       // [16]
    float* pp         = (float*)(smem + QT * LK * 2 + 1088);       // [12][16][16]

    int bid = blockIdx.x;
    int swz = (bid & 7) * 256 + (bid >> 3);   // bijective XCD swizzle (2048 % 8 == 0)
    int b = swz >> 7;
    int q0 = (swz & 127) * QT;

    int tid = threadIdx.x;
    int lane = tid & 63;
    int wave = tid >> 6;
    int lr = lane & 15, lg = lane >> 4;

    // Q fragments (B-operand of S^T = K·Q^T): lane holds Q[q0+lr][8*lg+i]
    bf16x8 qf0, qf1;
    {
        const unsigned short* qp = qb + ((int64_t)(b * LQ + q0 + lr)) * DH + 8 * lg;
        qf0 = *(const bf16x8*)qp;
        qf1 = *(const bf16x8*)(qp + 32);
    }

    float dsum = 0.f;

    // ---- phase 1: S^T MFMA + inline mask-select + exp -> LDS.
    //      All VMEM via inline asm, 3-deep {mask,K0,K1} triple ring, counted
    //      vmcnt (6,6,6,6,6,6,3,0) so ~2 triples stay in flight per wave. ----
    {
        const unsigned short* kpw =
            kb + (int64_t)b * LK * DH + (wave * 16 + lr) * DH + 8 * lg;
        const float* mrow =
            mask + ((int64_t)(b * LQ + q0 + lr)) * LK + wave * 16 + lg * 4;

        f32x4  mk[3];
        bf16x8 ka[3], kb_[3];
        #pragma unroll
        for (int t = 0; t < 3; ++t) {          // prologue: issue triples 0,1,2
            ld_f32x4(mk[t], mrow + t * STRIP);
            ld_bf16x8(ka[t],  kpw + (int64_t)t * STRIP * DH);
            ld_bf16x8(kb_[t], kpw + (int64_t)t * STRIP * DH + 32);
        }
        #pragma unroll
        for (int kt = 0; kt < NIT; ++kt) {
            int s = kt % 3;
            // counted wait for triple kt; tie regs so consumers can't hoist
            if (kt < 6)
                asm volatile("s_waitcnt vmcnt(6)"
                             : "+v"(mk[s]), "+v"(ka[s]), "+v"(kb_[s]));
            else if (kt == 6)
                asm volatile("s_waitcnt vmcnt(3)"
                             : "+v"(mk[s]), "+v"(ka[s]), "+v"(kb_[s]));
            else
                asm volatile("s_waitcnt vmcnt(0)"
                             : "+v"(mk[s]), "+v"(ka[s]), "+v"(kb_[s]));
            __builtin_amdgcn_sched_barrier(0);

            f32x4 acc = {0.f, 0.f, 0.f, 0.f};
            acc = __builtin_amdgcn_mfma_f32_16x16x32_bf16(ka[s],  qf0, acc, 0, 0, 0);
            acc = __builtin_amdgcn_mfma_f32_16x16x32_bf16(kb_[s], qf1, acc, 0, 0, 0);
            // C[row=lg*4+j][col=lr] = S[q=lr][key = kt*STRIP + wave*16 + lg*4 + j]
            unsigned short eb[4];
            #pragma unroll
            for (int j = 0; j < 4; ++j) {
                float sc = acc[j] * 0.125f;
                sc = fminf(fmaxf(sc, -15.0f), 15.0f);
                unsigned short p = f2bf(__expf(sc));
                eb[j] = (mk[s][j] != 0.f) ? p : (unsigned short)0;
                dsum += bf2f(eb[j]);
            }
            uint2 u;
            u.x = (uint32_t)eb[0] | ((uint32_t)eb[1] << 16);
            u.y = (uint32_t)eb[2] | ((uint32_t)eb[3] << 16);
            int c = kt * STRIP + wave * 16 + lg * 4;
            int byteoff = (lr * 4096 + c * 2) ^ ((lr & 7) << 4);
            *(uint2*)(smem + byteoff) = u;

            if (kt < NIT - 3) {                // issue triple kt+3 into slot s
                ld_f32x4(mk[s], mrow + (kt + 3) * STRIP);
                ld_bf16x8(ka[s],  kpw + (int64_t)(kt + 3) * STRIP * DH);
                ld_bf16x8(kb_[s], kpw + (int64_t)(kt + 3) * STRIP * DH + 32);
            }
        }
    }

    // per-row partial denominators: sum over lg (4 lanes per row)
    dsum += __shfl_xor(dsum, 16);
    dsum += __shfl_xor(dsum, 32);
    if (lane < 16) denom_part[wave * 16 + lane] = dsum;
    __syncthreads();

    // ---- phase 2: attn row write-out (regular stores, line-combined) ----
    {
        int r = wave;
        float den = 1e-6f;
        #pragma unroll
        for (int w = 0; w < NW; ++w) den += denom_part[w * 16 + r];
        if (lane == 0) denF[r] = den;
        float inv = 1.0f / den;
        float* ap = attn + ((int64_t)(b * LQ + q0 + r)) * LK;
        int rowbase = r * 4096;
        int sw = (r & 7) << 4;
        int c0l = lane * 8;
        #pragma unroll
        for (int i = 0; i < 4; ++i) {
            int byteoff = (rowbase + (i * 512 + c0l) * 2) ^ sw;
            bf16x8 ev = *(const bf16x8*)(smem + byteoff);
            f32x4 o0, o1;
            o0[0] = bf2f((unsigned short)ev[0]) * inv;
            o0[1] = bf2f((unsigned short)ev[1]) * inv;
            o0[2] = bf2f((unsigned short)ev[2]) * inv;
            o0[3] = bf2f((unsigned short)ev[3]) * inv;
            o1[0] = bf2f((unsigned short)ev[4]) * inv;
            o1[1] = bf2f((unsigned short)ev[5]) * inv;
            o1[2] = bf2f((unsigned short)ev[6]) * inv;
            o1[3] = bf2f((unsigned short)ev[7]) * inv;
            *(f32x4*)(ap + i * 512 + c0l) = o0;
            *(f32x4*)(ap + i * 512 + c0l + 4) = o1;
        }
    }

    // ---- phase 3: PV; wave w -> col-tile (w&3)*16, K-quarter w>>2 ----
    f32x4 pacc = {0.f, 0.f, 0.f, 0.f};
    int cw = (wave & 3) * 16, kq = wave >> 2;
    {
        const unsigned short* vp =
            vtb + ((int64_t)(b * DH + cw + lr)) * LK + kq * 512 + 8 * lg;
        int rowbase = lr * 4096;
        int sw = (lr & 7) << 4;
        int kk0 = kq * 512;
        #pragma unroll 4
        for (int kk = 0; kk < 512; kk += 32) {
            int byteoff = (rowbase + (kk0 + kk + 8 * lg) * 2) ^ sw;
            bf16x8 ef = *(const bf16x8*)(smem + byteoff);
            bf16x8 vf = *(const bf16x8*)(vp + kk);
            pacc = __builtin_amdgcn_mfma_f32_16x16x32_bf16(ef, vf, pacc, 0, 0, 0);
        }
    }
    if (kq != 0) {
        #pragma unroll
        for (int j = 0; j < 4; ++j)
            pp[((kq - 1) * 4 + (wave & 3)) * 256 + (lg * 4 + j) * 16 + lr] = pacc[j];
    }
    __syncthreads();
    if (kq == 0) {
        int c4 = wave & 3;
        #pragma unroll
        for (int j = 0; j < 4; ++j) {
            int r = lg * 4 + j;
            float den = denF[r];
            float val = pacc[j] + pp[(c4) * 256 + r * 16 + lr] +
                        pp[(4 + c4) * 256 + r * 16 + lr] +
                        pp[(8 + c4) * 256 + r * 16 + lr];
            out[((int64_t)(b * LQ + q0 + r)) * DH + cw + lr] = val / den;
        }
    }
}

extern "C" void kernel_launch(void* const* d_in, const int* in_sizes, int n_in,
                              void* d_out, int out_size, void* d_ws, size_t ws_size,
                              hipStream_t stream) {
    const float* q    = (const float*)d_in[0];
    const float* k    = (const float*)d_in[1];
    const float* v    = (const float*)d_in[2];
    const float* mask = (const float*)d_in[3];
    float* out  = (float*)d_out;
    float* attn = out + (int64_t)NB * LQ * DH;

    unsigned short* qb  = (unsigned short*)d_ws;
    unsigned short* kb  = qb + (int64_t)NB * LQ * DH;
    unsigned short* vtb = kb + (int64_t)NB * LK * DH;

    (void)hipFuncSetAttribute((const void*)attn_kernel,
                              hipFuncAttributeMaxDynamicSharedMemorySize, 78912);

    convert_kernel<<<2560, 256, 0, stream>>>(q, k, v, qb, kb, vtb);
    attn_kernel<<<2048, 1024, 78912, stream>>>(qb, kb, vtb, mask, out, attn);
}